// Round 19
// baseline (64.769 us; speedup 1.0000x reference)
//
#include <hip/hip_runtime.h>
#include <math.h>

// Problem constants (fixed by the reference)
#define NB   8        // batch
#define LQN  4096     // queries
#define DM   256      // d_model
#define MH   8        // heads
#define PP   4        // points
#define HH   64       // H
#define WW   64       // W
#define PW   67       // padded image width/height (x,y in -1..65)
#define PPIX (PW*PW)  // 4489 padded pixels per batch
#define LSTR 104      // sL row stride in ushorts (96 real cols + 8 pad)

typedef __bf16 bf16x8 __attribute__((ext_vector_type(8)));
typedef float  f32x4  __attribute__((ext_vector_type(4)));
typedef unsigned short us8 __attribute__((ext_vector_type(8)));
typedef unsigned short us4 __attribute__((ext_vector_type(4)));

__device__ __forceinline__ unsigned short f2bf(float f) {   // RNE fp32 -> bf16 bits
    unsigned u = __float_as_uint(f);
    u += 0x7FFFu + ((u >> 16) & 1u);
    return (unsigned short)(u >> 16);
}
__device__ __forceinline__ float bf2f(unsigned short b) {
    return __uint_as_float((unsigned)b << 16);
}

__device__ __forceinline__ void gl2lds16(const void* g, unsigned short* l) {
    __builtin_amdgcn_global_load_lds(
        (const __attribute__((address_space(1))) void*)g,
        (__attribute__((address_space(3))) void*)l,
        16, 0, 0);
}

// Convert a swizzled fp32 LDS row-pair (two 16B units) to a bf16x8 fragment.
// LDS layout: [rows][8 units of 16B], unit for k-quad q of row r at
// r*8 + (q ^ (r&7)); write side is linear DMA dest + XOR-swizzled global src.
__device__ __forceinline__ bf16x8 cvt_frag(const unsigned short* s, int row, int kq) {
    const int u0 = row * 8 + ((kq * 2) ^ (row & 7));
    const int u1 = u0 ^ 1;
    const f32x4 a0 = *(const f32x4*)&s[u0 * 8];
    const f32x4 a1 = *(const f32x4*)&s[u1 * 8];
    bf16x8 v;
    v[0] = (__bf16)a0[0]; v[1] = (__bf16)a0[1];
    v[2] = (__bf16)a0[2]; v[3] = (__bf16)a0[3];
    v[4] = (__bf16)a1[0]; v[5] = (__bf16)a1[1];
    v[6] = (__bf16)a1[2]; v[7] = (__bf16)a1[3];
    return v;
}

// ---------------------------------------------------------------------------
// Prep: weight bf16 conversion (Wvh [256][256]; Woh [256][256]; Wcath
// [128][256] rows 96-127 zero; bcat fp32[128]) + padded-image border zero.
// ---------------------------------------------------------------------------
__global__ __launch_bounds__(256)
void prep_kernel(const float* __restrict__ Wv, const float* __restrict__ Wo,
                 const float* __restrict__ Woff, const float* __restrict__ Wa,
                 const float* __restrict__ boff, const float* __restrict__ ba,
                 unsigned short* __restrict__ Wvh, unsigned short* __restrict__ Woh,
                 unsigned short* __restrict__ Wcath, float* __restrict__ bcat,
                 unsigned short* __restrict__ valueP) {
    const int i = blockIdx.x * 256 + threadIdx.x;
    if (i < 65536) {
        Wvh[i] = f2bf(Wv[i]);
    } else if (i < 131072) {
        const int j = i - 65536;
        Woh[j] = f2bf(Wo[j]);
    } else if (i < 163840) {
        const int j = i - 131072, n = j >> 8, k = j & 255;
        const float v = (n < 64) ? Woff[n * 256 + k]
                                 : ((n < 96) ? Wa[(n - 64) * 256 + k] : 0.f);
        Wcath[j] = f2bf(v);
    } else if (i < 163968) {
        const int n = i - 163840;
        bcat[n] = (n < 64) ? boff[n] : ((n < 96) ? ba[n - 64] : 0.f);
    } else if (i < 163968 + 201216) {
        const int j   = i - 163968;
        const int c4  = j & 63;
        const int pix = j >> 6;
        const int n   = pix / 393;
        const int r   = pix - n * 393;
        int x, y;
        if (r < 201) {
            const int q = r / 67;
            y = (q == 0) ? 0 : (q == 1 ? 65 : 66);
            x = r - q * 67;
        } else {
            const int q = r - 201;
            y = 1 + q / 3;
            const int s = q - (q / 3) * 3;
            x = (s == 0) ? 0 : (s == 1 ? 65 : 66);
        }
        const size_t addr = ((size_t)n * PPIX + (size_t)y * PW + x) * DM + c4 * 4;
        *(ushort4*)&valueP[addr] = make_ushort4(0, 0, 0, 0);
    }
}

// ---------------------------------------------------------------------------
// Value GEMM (proven): BM=64/BN=128, batch<->XCD affine, 2-deep counted
// vmcnt pipeline, A fp32 gl2lds swizzled + read cvt, bf16 scatter into the
// padded value image.
// ---------------------------------------------------------------------------
__global__ __launch_bounds__(256, 4)
void value_gemm(const float* __restrict__ Ain,
                const unsigned short* __restrict__ Wvh,
                const float* __restrict__ bv,
                unsigned short* __restrict__ valueP) {
    constexpr int K = 256, NK = 8;
    __shared__ unsigned short sA[2][4096];   // [64][32] fp32, swizzled units
    __shared__ unsigned short sB[2][4096];   // [128][32] bf16 linear

    const int t   = threadIdx.x;
    const int blk = blockIdx.x;              // 0..1023
    const int xb  = blk & 7;                 // batch = XCD
    const int idx = blk >> 3;                // 0..127
    const int brow = xb * 4096 + (idx >> 1) * 64;
    const int bcol = (idx & 1) * 128;

    const int srow = t >> 3;
    const int scq  = (t & 7) ^ (srow & 7);
    const float* aG = Ain + (size_t)(brow + srow) * K + scq * 4;
    const size_t aI = (size_t)32 * K;

    const unsigned short* bG = Wvh + (size_t)(bcol + (t >> 2)) * K + (t & 3) * 8;
    const size_t bI = (size_t)64 * K;

    const int l   = t & 63;
    const int wid = t >> 6;
    const int wr  = wid >> 1, wc = wid & 1;
    const int fr  = l & 15,   kq = l >> 4;

    f32x4 acc[2][4] = {};

#define STAGE(buf, ks_) { const int k0_ = (ks_) * 32;                    \
       gl2lds16(aG + k0_,      &sA[buf][t * 8]);                         \
       gl2lds16(aG + k0_ + aI, &sA[buf][2048 + t * 8]);                  \
       gl2lds16(bG + k0_,      &sB[buf][t * 8]);                         \
       gl2lds16(bG + k0_ + bI, &sB[buf][2048 + t * 8]); }

    STAGE(0, 0);
    STAGE(1, 1);

    for (int ks = 0; ks < NK; ++ks) {
        const int cur = ks & 1;
        if (ks < NK - 1) asm volatile("s_waitcnt vmcnt(4)" ::: "memory");
        else             asm volatile("s_waitcnt vmcnt(0)" ::: "memory");
        __builtin_amdgcn_s_barrier();
        __builtin_amdgcn_sched_barrier(0);

        bf16x8 af[2], bf_[4];
#pragma unroll
        for (int m = 0; m < 2; ++m)
            af[m]  = cvt_frag(sA[cur], wr * 32 + m * 16 + fr, kq);
#pragma unroll
        for (int n = 0; n < 4; ++n)
            bf_[n] = *(const bf16x8*)&sB[cur][(wc * 64 + n * 16 + fr) * 32 + kq * 8];

#pragma unroll
        for (int m = 0; m < 2; ++m)
#pragma unroll
            for (int n = 0; n < 4; ++n)
                acc[m][n] = __builtin_amdgcn_mfma_f32_16x16x32_bf16(
                    bf_[n], af[m], acc[m][n], 0, 0, 0);

        __builtin_amdgcn_sched_barrier(0);
        __builtin_amdgcn_s_barrier();
        if (ks + 2 < NK) STAGE(cur, ks + 2);
    }
#undef STAGE

#pragma unroll
    for (int m = 0; m < 2; ++m) {
        const int row = brow + wr * 32 + m * 16 + fr;
        const int nb_ = row >> 12;
        const int pix = row & 4095;
        const int y   = pix >> 6, x = pix & 63;
        const size_t rbase =
            ((size_t)nb_ * PPIX + (size_t)(y + 1) * PW + (x + 1)) * DM;
#pragma unroll
        for (int n = 0; n < 4; ++n) {
            const int colq = bcol + wc * 64 + n * 16 + kq * 4;
            const float4 b4 = *(const float4*)&bv[colq];
            us4 o;
            o[0] = f2bf(acc[m][n][0] + b4.x);
            o[1] = f2bf(acc[m][n][1] + b4.y);
            o[2] = f2bf(acc[m][n][2] + b4.z);
            o[3] = f2bf(acc[m][n][3] + b4.w);
            *(us4*)&valueP[rbase + colq] = o;
        }
    }
}

// ---------------------------------------------------------------------------
// FUSED logits-GEMM + sampling + out-GEMM, 64-query tile. 512 thr = 8 waves.
// LDS DIET: 48 KB total -> 3 blocks/CU (24 waves/CU, was 2 blocks at 80 KB).
//   region sS  (32 KB): ph0 sQ/sW staging dbuf; ph1/2 sampled tile [64][256]
//   region sU  (16 KB): ph0/1 logits sL (stride 104, 13.3 KB);
//                       ph2 single-buffered Woh B tile [256][32]
// Phase 0: logits[64][96] = query @ Wcath^T + bcat -> sL (2-deep counted).
// Phase 1: 2-query software-pipelined sampling.
// Phase 2: out[64x256] = sS @ Woh^T + bo; B SINGLE-buffered (vmcnt(0)/step;
//          cross-block TLP at 3 blocks/CU hides the stage latency).
// ---------------------------------------------------------------------------
__global__ __launch_bounds__(512, 6)
void fused_lso(const float* __restrict__ query, const float* __restrict__ refp,
               const unsigned short* __restrict__ valueP,
               const unsigned short* __restrict__ Wcath,
               const float* __restrict__ bcat,
               const unsigned short* __restrict__ Woh,
               const float* __restrict__ bo, float* __restrict__ C) {
    constexpr int K = 256, NK = 8;
    extern __shared__ unsigned short smem[];
    unsigned short* sS = smem;            // 32KB region
    unsigned short* sU = smem + 16384;    // 16KB region (sL / ph2 B union)

    const int t    = threadIdx.x;
    const int blk  = blockIdx.x;          // 0..511
    const int nb   = blk & 7;             // batch = XCD
    const int brow = nb * 4096 + (blk >> 3) * 64;
    const int w    = t >> 6;              // wave 0..7
    const int lane = t & 63;
    const int fr   = lane & 15, kq = lane >> 4;

    // ===== Phase 0: logits = query[64x256] @ Wcath^T + bcat -> sL =====
    {
        unsigned short* sQ = sS;          // [2][4096] fp32 swizzled (16KB)
        unsigned short* sW = sS + 8192;   // [2][4096] bf16 linear  (16KB)
        unsigned short* sL = sU;          // [64][LSTR]

        const int srow = t >> 3;          // 0..63
        const int scq  = (t & 7) ^ (srow & 7);
        const float* aG = query + (size_t)(brow + srow) * K + scq * 4;
        const unsigned short* wG = Wcath + (size_t)(t >> 2) * K + (t & 3) * 8;

        const int wr0 = w >> 2;           // 0..1 : 32-row half
        const int wc0 = w & 3;            // 0..3 : 32-col quarter

        f32x4 acc[2][2] = {};

#define STG0(buf, ks_) { const int k0_ = (ks_) * 32;                     \
       gl2lds16(aG + k0_, &sQ[(buf) * 4096 + t * 8]);                    \
       gl2lds16(wG + k0_, &sW[(buf) * 4096 + t * 8]); }

        STG0(0, 0);
        STG0(1, 1);

        for (int ks = 0; ks < NK; ++ks) {
            const int cur = ks & 1;
            if (ks < NK - 1) asm volatile("s_waitcnt vmcnt(2)" ::: "memory");
            else             asm volatile("s_waitcnt vmcnt(0)" ::: "memory");
            __builtin_amdgcn_s_barrier();
            __builtin_amdgcn_sched_barrier(0);

            bf16x8 af[2], bw[2];
#pragma unroll
            for (int m = 0; m < 2; ++m)
                af[m] = cvt_frag(&sQ[cur * 4096], wr0 * 32 + m * 16 + fr, kq);
#pragma unroll
            for (int n = 0; n < 2; ++n)
                bw[n] = *(const bf16x8*)&sW[cur * 4096 +
                        (wc0 * 32 + n * 16 + fr) * 32 + kq * 8];

#pragma unroll
            for (int m = 0; m < 2; ++m)
#pragma unroll
                for (int n = 0; n < 2; ++n)
                    acc[m][n] = __builtin_amdgcn_mfma_f32_16x16x32_bf16(
                        bw[n], af[m], acc[m][n], 0, 0, 0);

            __builtin_amdgcn_sched_barrier(0);
            __builtin_amdgcn_s_barrier();
            if (ks + 2 < NK) STG0(cur, ks + 2);
        }
#undef STG0

#pragma unroll
        for (int m = 0; m < 2; ++m) {
            const int row = wr0 * 32 + m * 16 + fr;
#pragma unroll
            for (int n = 0; n < 2; ++n) {
                const int colq = wc0 * 32 + n * 16 + kq * 4;
                if (colq < 96) {          // cols 96-127 are padding, never read
                    const float4 b4 = *(const float4*)&bcat[colq];
                    us4 o;
                    o[0] = f2bf(acc[m][n][0] + b4.x);
                    o[1] = f2bf(acc[m][n][1] + b4.y);
                    o[2] = f2bf(acc[m][n][2] + b4.z);
                    o[3] = f2bf(acc[m][n][3] + b4.w);
                    *(us4*)&sL[row * LSTR + colq] = o;
                }
            }
        }
    }
    __syncthreads();                      // logits ready; sQ/sW dead

    // ===== Phase 1: sample 8 queries per wave, 2-query pipelined =====
    {
        const unsigned short* sL = sU;
        const int tp  = lane & 31;
        const int pm  = tp >> 2, ppt = tp & 3;
        const int half = lane >> 5;
        const int c8   = lane & 31;
        const int mh   = c8 >> 2;
        const unsigned short* vbase = valueP + (size_t)nb * (PPIX * DM) + c8 * 8;

        for (int i = 0; i < 8; i += 2) {
            const int qa = w * 8 + i;
            const int qb = qa + 1;

            // ---- setup + issue gathers, query A ----
            us8 gA0[4], gB0[4]; float wA0[4], wB0[4];
            {
                const unsigned short* lg = sL + qa * LSTR;
                const int b = brow + qa;
                const float rx = refp[(size_t)b * 2 + 0];
                const float ry = refp[(size_t)b * 2 + 1];
                const float ox = bf2f(lg[pm * 8 + ppt * 2 + 0]);
                const float oy = bf2f(lg[pm * 8 + ppt * 2 + 1]);
                const float la = bf2f(lg[64 + tp]);
                const float x = fminf(fmaxf(fmaf(rx, (float)WW, ox) - 0.5f, -1.0f), 64.0f);
                const float y = fminf(fmaxf(fmaf(ry, (float)HH, oy) - 0.5f, -1.0f), 64.0f);
                float mx = fmaxf(la, __shfl_xor(la, 1));
                mx = fmaxf(mx, __shfl_xor(mx, 2));
                const float e = __expf(la - mx);
                float den = e + __shfl_xor(e, 1);
                den += __shfl_xor(den, 2);
                const float wgt = e / den;
#pragma unroll
                for (int p = 0; p < PP; ++p) {
                    const int   sl = mh * PP + p;
                    const float xp = __shfl(x, sl);
                    const float yp = __shfl(y, sl);
                    const float wp = __shfl(wgt, sl);
                    const float x0f = floorf(xp), y0f = floorf(yp);
                    const int   x0 = (int)x0f,   y0 = (int)y0f;
                    const float wx1 = xp - x0f,  wy1 = yp - y0f;
                    const float wy  = half ? wy1 : (1.f - wy1);
                    wA0[p] = wp * wy * (1.f - wx1);
                    wB0[p] = wp * wy * wx1;
                    const unsigned short* p0 =
                        vbase + (size_t)((y0 + 1 + half) * PW + (x0 + 1)) * DM;
                    gA0[p] = *(const us8*)(p0);
                    gB0[p] = *(const us8*)(p0 + DM);
                }
            }

            // ---- setup + issue gathers, query B (overlaps A's latency) ----
            us8 gA1[4], gB1[4]; float wA1[4], wB1[4];
            {
                const unsigned short* lg = sL + qb * LSTR;
                const int b = brow + qb;
                const float rx = refp[(size_t)b * 2 + 0];
                const float ry = refp[(size_t)b * 2 + 1];
                const float ox = bf2f(lg[pm * 8 + ppt * 2 + 0]);
                const float oy = bf2f(lg[pm * 8 + ppt * 2 + 1]);
                const float la = bf2f(lg[64 + tp]);
                const float x = fminf(fmaxf(fmaf(rx, (float)WW, ox) - 0.5f, -1.0f), 64.0f);
                const float y = fminf(fmaxf(fmaf(ry, (float)HH, oy) - 0.5f, -1.0f), 64.0f);
                float mx = fmaxf(la, __shfl_xor(la, 1));
                mx = fmaxf(mx, __shfl_xor(mx, 2));
                const float e = __expf(la - mx);
                float den = e + __shfl_xor(e, 1);
                den += __shfl_xor(den, 2);
                const float wgt = e / den;
#pragma unroll
                for (int p = 0; p < PP; ++p) {
                    const int   sl = mh * PP + p;
                    const float xp = __shfl(x, sl);
                    const float yp = __shfl(y, sl);
                    const float wp = __shfl(wgt, sl);
                    const float x0f = floorf(xp), y0f = floorf(yp);
                    const int   x0 = (int)x0f,   y0 = (int)y0f;
                    const float wx1 = xp - x0f,  wy1 = yp - y0f;
                    const float wy  = half ? wy1 : (1.f - wy1);
                    wA1[p] = wp * wy * (1.f - wx1);
                    wB1[p] = wp * wy * wx1;
                    const unsigned short* p0 =
                        vbase + (size_t)((y0 + 1 + half) * PW + (x0 + 1)) * DM;
                    gA1[p] = *(const us8*)(p0);
                    gB1[p] = *(const us8*)(p0 + DM);
                }
            }

            // ---- FMA + reduce + store, query A ----
            {
                float accv[8] = {};
#pragma unroll
                for (int p = 0; p < PP; ++p)
#pragma unroll
                    for (int j = 0; j < 8; ++j) {
                        accv[j] = fmaf(wA0[p], bf2f(gA0[p][j]), accv[j]);
                        accv[j] = fmaf(wB0[p], bf2f(gB0[p][j]), accv[j]);
                    }
#pragma unroll
                for (int j = 0; j < 8; ++j)
                    accv[j] += __shfl_xor(accv[j], 32);
                if (half == 0) {
                    us8 o;
#pragma unroll
                    for (int j = 0; j < 8; ++j) o[j] = f2bf(accv[j]);
                    *(us8*)&sS[qa * 256 + ((c8 ^ (qa & 7)) * 8)] = o;
                }
            }
            // ---- FMA + reduce + store, query B ----
            {
                float accv[8] = {};
#pragma unroll
                for (int p = 0; p < PP; ++p)
#pragma unroll
                    for (int j = 0; j < 8; ++j) {
                        accv[j] = fmaf(wA1[p], bf2f(gA1[p][j]), accv[j]);
                        accv[j] = fmaf(wB1[p], bf2f(gB1[p][j]), accv[j]);
                    }
#pragma unroll
                for (int j = 0; j < 8; ++j)
                    accv[j] += __shfl_xor(accv[j], 32);
                if (half == 0) {
                    us8 o;
#pragma unroll
                    for (int j = 0; j < 8; ++j) o[j] = f2bf(accv[j]);
                    *(us8*)&sS[qb * 256 + ((c8 ^ (qb & 7)) * 8)] = o;
                }
            }
        }
    }
    __syncthreads();                      // sampled tile complete; sL dead

    // ===== Phase 2: out[64x256] = sS @ Woh^T + bo (B single-buffered in sU)
    const unsigned short* bG = Woh + (size_t)(t >> 2) * K + (t & 3) * 8;
    const size_t rHalf = (size_t)128 * K;

    const int wr = w >> 2, wc = w & 3;    // wave tile 32 rows x 64 cols

    f32x4 acc[2][4] = {};

#define STAGEF(ks_) { const int k0_ = (ks_) * 32;                        \
       gl2lds16(bG + k0_,         &sU[t * 8]);                           \
       gl2lds16(bG + k0_ + rHalf, &sU[4096 + t * 8]); }

    STAGEF(0);

    for (int ks = 0; ks < NK; ++ks) {
        asm volatile("s_waitcnt vmcnt(0)" ::: "memory");
        __builtin_amdgcn_s_barrier();     // B tile for step ks ready
        __builtin_amdgcn_sched_barrier(0);

        bf16x8 af[2], bfr[4];
#pragma unroll
        for (int m = 0; m < 2; ++m) {
            const int row = wr * 32 + m * 16 + fr;
            const int u   = (ks * 4 + kq) ^ (row & 7);
            af[m] = *(const bf16x8*)&sS[row * 256 + u * 8];
        }
#pragma unroll
        for (int n = 0; n < 4; ++n)
            bfr[n] = *(const bf16x8*)&sU[(wc * 64 + n * 16 + fr) * 32 + kq * 8];

#pragma unroll
        for (int m = 0; m < 2; ++m)
#pragma unroll
            for (int n = 0; n < 4; ++n)   // swapped: C[m16+fr][n16+kq4+j]
                acc[m][n] = __builtin_amdgcn_mfma_f32_16x16x32_bf16(
                    bfr[n], af[m], acc[m][n], 0, 0, 0);

        __builtin_amdgcn_sched_barrier(0);
        __builtin_amdgcn_s_barrier();     // all waves done reading sU
        if (ks + 1 < NK) STAGEF(ks + 1);
    }
#undef STAGEF

#pragma unroll
    for (int m = 0; m < 2; ++m) {
        const int row = brow + wr * 32 + m * 16 + fr;
#pragma unroll
        for (int n = 0; n < 4; ++n) {
            const int colq = wc * 64 + n * 16 + kq * 4;
            const float4 bs = *(const float4*)&bo[colq];
            float4 o;
            o.x = acc[m][n][0] + bs.x; o.y = acc[m][n][1] + bs.y;
            o.z = acc[m][n][2] + bs.z; o.w = acc[m][n][3] + bs.w;
            *(float4*)&C[(size_t)row * DM + colq] = o;
        }
    }
}

// ---------------------------------------------------------------------------
extern "C" void kernel_launch(void* const* d_in, const int* in_sizes, int n_in,
                              void* d_out, int out_size, void* d_ws, size_t ws_size,
                              hipStream_t stream) {
    const float* query  = (const float*)d_in[0];   // [8,4096,256]
    const float* refp   = (const float*)d_in[1];   // [8,4096,2]
    const float* inputf = (const float*)d_in[2];   // [8,4096,256]
    const float* Wv   = (const float*)d_in[5];     // [256,256]
    const float* bv   = (const float*)d_in[6];     // [256]
    const float* Woff = (const float*)d_in[7];     // [64,256]
    const float* boff = (const float*)d_in[8];     // [64]
    const float* Wa   = (const float*)d_in[9];     // [32,256]
    const float* ba   = (const float*)d_in[10];    // [32]
    const float* Wo   = (const float*)d_in[11];    // [256,256]
    const float* bo   = (const float*)d_in[12];    // [256]
    float* out = (float*)d_out;

    // workspace layout (ushort units)
    unsigned short* valueP = (unsigned short*)d_ws;            //  9,193,472
    unsigned short* Wvh    = valueP + (size_t)NB * PPIX * DM;  //     65,536
    unsigned short* Woh    = Wvh    + 65536;                   //     65,536
    unsigned short* Wcath  = Woh    + 65536;                   //     32,768
    float*          bcat   = (float*)(Wcath + 32768);          //        128

    // 1. prep: weight bf16 conversion + image border zero
    prep_kernel<<<1427, 256, 0, stream>>>(Wv, Wo, Woff, Wa, boff, ba,
                                          Wvh, Woh, Wcath, bcat, valueP);

    // 2. value GEMM (BM=64, batch<->XCD affine, counted vmcnt)
    value_gemm<<<1024, 256, 0, stream>>>(inputf, Wvh, bv, valueP);

    // 3. fused logits GEMM + sampling + out GEMM (48 KB dyn LDS, 3 blocks/CU)
    fused_lso<<<512, 512, 49152, stream>>>(query, refp, valueP, Wcath, bcat,
                                           Woh, bo, out);
}

// Round 20
// 58.462 us; speedup vs baseline: 1.1079x; 1.1079x over previous
//
#include <hip/hip_runtime.h>
#include <math.h>

// Problem constants (fixed by the reference)
#define NB   8        // batch
#define LQN  4096     // queries
#define DM   256      // d_model
#define MH   8        // heads
#define PP   4        // points
#define HH   64       // H
#define WW   64       // W
#define PW   67       // padded image width/height (x,y in -1..65)
#define PPIX (PW*PW)  // 4489 padded pixels per batch

typedef __bf16 bf16x8 __attribute__((ext_vector_type(8)));
typedef float  f32x4  __attribute__((ext_vector_type(4)));
typedef unsigned short us8 __attribute__((ext_vector_type(8)));
typedef unsigned short us4 __attribute__((ext_vector_type(4)));

__device__ __forceinline__ unsigned short f2bf(float f) {   // RNE fp32 -> bf16 bits
    unsigned u = __float_as_uint(f);
    u += 0x7FFFu + ((u >> 16) & 1u);
    return (unsigned short)(u >> 16);
}
__device__ __forceinline__ float bf2f(unsigned short b) {
    return __uint_as_float((unsigned)b << 16);
}

__device__ __forceinline__ void gl2lds16(const void* g, unsigned short* l) {
    __builtin_amdgcn_global_load_lds(
        (const __attribute__((address_space(1))) void*)g,
        (__attribute__((address_space(3))) void*)l,
        16, 0, 0);
}

// Convert a swizzled fp32 LDS row-pair (two 16B units) to a bf16x8 fragment.
// LDS layout: [rows][8 units of 16B], unit for k-quad q of row r at
// r*8 + (q ^ (r&7)); write side is linear DMA dest + XOR-swizzled global src.
__device__ __forceinline__ bf16x8 cvt_frag(const unsigned short* s, int row, int kq) {
    const int u0 = row * 8 + ((kq * 2) ^ (row & 7));
    const int u1 = u0 ^ 1;
    const f32x4 a0 = *(const f32x4*)&s[u0 * 8];
    const f32x4 a1 = *(const f32x4*)&s[u1 * 8];
    bf16x8 v;
    v[0] = (__bf16)a0[0]; v[1] = (__bf16)a0[1];
    v[2] = (__bf16)a0[2]; v[3] = (__bf16)a0[3];
    v[4] = (__bf16)a1[0]; v[5] = (__bf16)a1[1];
    v[6] = (__bf16)a1[2]; v[7] = (__bf16)a1[3];
    return v;
}

// ---------------------------------------------------------------------------
// Prep: weight bf16 conversion (Wvh [256][256]; Woh [256][256]; Wcath
// [128][256] rows 96-127 zero; bcat fp32[128]) + padded-image border zero.
// ---------------------------------------------------------------------------
__global__ __launch_bounds__(256)
void prep_kernel(const float* __restrict__ Wv, const float* __restrict__ Wo,
                 const float* __restrict__ Woff, const float* __restrict__ Wa,
                 const float* __restrict__ boff, const float* __restrict__ ba,
                 unsigned short* __restrict__ Wvh, unsigned short* __restrict__ Woh,
                 unsigned short* __restrict__ Wcath, float* __restrict__ bcat,
                 unsigned short* __restrict__ valueP) {
    const int i = blockIdx.x * 256 + threadIdx.x;
    if (i < 65536) {
        Wvh[i] = f2bf(Wv[i]);
    } else if (i < 131072) {
        const int j = i - 65536;
        Woh[j] = f2bf(Wo[j]);
    } else if (i < 163840) {
        const int j = i - 131072, n = j >> 8, k = j & 255;
        const float v = (n < 64) ? Woff[n * 256 + k]
                                 : ((n < 96) ? Wa[(n - 64) * 256 + k] : 0.f);
        Wcath[j] = f2bf(v);
    } else if (i < 163968) {
        const int n = i - 163840;
        bcat[n] = (n < 64) ? boff[n] : ((n < 96) ? ba[n - 64] : 0.f);
    } else if (i < 163968 + 201216) {
        const int j   = i - 163968;
        const int c4  = j & 63;
        const int pix = j >> 6;
        const int n   = pix / 393;
        const int r   = pix - n * 393;
        int x, y;
        if (r < 201) {
            const int q = r / 67;
            y = (q == 0) ? 0 : (q == 1 ? 65 : 66);
            x = r - q * 67;
        } else {
            const int q = r - 201;
            y = 1 + q / 3;
            const int s = q - (q / 3) * 3;
            x = (s == 0) ? 0 : (s == 1 ? 65 : 66);
        }
        const size_t addr = ((size_t)n * PPIX + (size_t)y * PW + x) * DM + c4 * 4;
        *(ushort4*)&valueP[addr] = make_ushort4(0, 0, 0, 0);
    }
}

// ---------------------------------------------------------------------------
// Value GEMM (proven): BM=64/BN=128, batch<->XCD affine, 2-deep counted
// vmcnt pipeline, A fp32 gl2lds swizzled + read cvt, bf16 scatter into the
// padded value image.
// ---------------------------------------------------------------------------
__global__ __launch_bounds__(256, 4)
void value_gemm(const float* __restrict__ Ain,
                const unsigned short* __restrict__ Wvh,
                const float* __restrict__ bv,
                unsigned short* __restrict__ valueP) {
    constexpr int K = 256, NK = 8;
    __shared__ unsigned short sA[2][4096];   // [64][32] fp32, swizzled units
    __shared__ unsigned short sB[2][4096];   // [128][32] bf16 linear

    const int t   = threadIdx.x;
    const int blk = blockIdx.x;              // 0..1023
    const int xb  = blk & 7;                 // batch = XCD
    const int idx = blk >> 3;                // 0..127
    const int brow = xb * 4096 + (idx >> 1) * 64;
    const int bcol = (idx & 1) * 128;

    const int srow = t >> 3;
    const int scq  = (t & 7) ^ (srow & 7);
    const float* aG = Ain + (size_t)(brow + srow) * K + scq * 4;
    const size_t aI = (size_t)32 * K;

    const unsigned short* bG = Wvh + (size_t)(bcol + (t >> 2)) * K + (t & 3) * 8;
    const size_t bI = (size_t)64 * K;

    const int l   = t & 63;
    const int wid = t >> 6;
    const int wr  = wid >> 1, wc = wid & 1;
    const int fr  = l & 15,   kq = l >> 4;

    f32x4 acc[2][4] = {};

#define STAGE(buf, ks_) { const int k0_ = (ks_) * 32;                    \
       gl2lds16(aG + k0_,      &sA[buf][t * 8]);                         \
       gl2lds16(aG + k0_ + aI, &sA[buf][2048 + t * 8]);                  \
       gl2lds16(bG + k0_,      &sB[buf][t * 8]);                         \
       gl2lds16(bG + k0_ + bI, &sB[buf][2048 + t * 8]); }

    STAGE(0, 0);
    STAGE(1, 1);

    for (int ks = 0; ks < NK; ++ks) {
        const int cur = ks & 1;
        if (ks < NK - 1) asm volatile("s_waitcnt vmcnt(4)" ::: "memory");
        else             asm volatile("s_waitcnt vmcnt(0)" ::: "memory");
        __builtin_amdgcn_s_barrier();
        __builtin_amdgcn_sched_barrier(0);

        bf16x8 af[2], bf_[4];
#pragma unroll
        for (int m = 0; m < 2; ++m)
            af[m]  = cvt_frag(sA[cur], wr * 32 + m * 16 + fr, kq);
#pragma unroll
        for (int n = 0; n < 4; ++n)
            bf_[n] = *(const bf16x8*)&sB[cur][(wc * 64 + n * 16 + fr) * 32 + kq * 8];

#pragma unroll
        for (int m = 0; m < 2; ++m)
#pragma unroll
            for (int n = 0; n < 4; ++n)
                acc[m][n] = __builtin_amdgcn_mfma_f32_16x16x32_bf16(
                    bf_[n], af[m], acc[m][n], 0, 0, 0);

        __builtin_amdgcn_sched_barrier(0);
        __builtin_amdgcn_s_barrier();
        if (ks + 2 < NK) STAGE(cur, ks + 2);
    }
#undef STAGE

#pragma unroll
    for (int m = 0; m < 2; ++m) {
        const int row = brow + wr * 32 + m * 16 + fr;
        const int nb_ = row >> 12;
        const int pix = row & 4095;
        const int y   = pix >> 6, x = pix & 63;
        const size_t rbase =
            ((size_t)nb_ * PPIX + (size_t)(y + 1) * PW + (x + 1)) * DM;
#pragma unroll
        for (int n = 0; n < 4; ++n) {
            const int colq = bcol + wc * 64 + n * 16 + kq * 4;
            const float4 b4 = *(const float4*)&bv[colq];
            us4 o;
            o[0] = f2bf(acc[m][n][0] + b4.x);
            o[1] = f2bf(acc[m][n][1] + b4.y);
            o[2] = f2bf(acc[m][n][2] + b4.z);
            o[3] = f2bf(acc[m][n][3] + b4.w);
            *(us4*)&valueP[rbase + colq] = o;
        }
    }
}

// ---------------------------------------------------------------------------
// FUSED logits-GEMM + sampling + out-GEMM, 64-query tile. 512 thr = 8 waves,
// 80 KB dyn LDS -> 2 blocks/CU. Batch-affine (batch = blk&7).
// Phase 0: logits[64][128] = query @ Wcath^T + bcat -> LDS sL (bf16).
// Phase 1: 2-query software-pipelined sampling.
// Phase 2: out[64x256] = sS @ Woh^T + bo; B lane-linear gl2lds dbuf.
// ---------------------------------------------------------------------------
__global__ __launch_bounds__(512, 4)
void fused_lso(const float* __restrict__ query, const float* __restrict__ refp,
               const unsigned short* __restrict__ valueP,
               const unsigned short* __restrict__ Wcath,
               const float* __restrict__ bcat,
               const unsigned short* __restrict__ Woh,
               const float* __restrict__ bo, float* __restrict__ C) {
    constexpr int K = 256, NK = 8;
    extern __shared__ unsigned short smem[];
    unsigned short* sS = smem;            // 32KB: ph0 A/B dbuf, ph1 sampled[64][256]
    unsigned short* sB = smem + 16384;    // 32KB: ph2 Woh dbuf [2][8192]
    unsigned short* sL = smem + 32768;    // 16KB: logits [64][128]

    const int t    = threadIdx.x;
    const int blk  = blockIdx.x;          // 0..511
    const int nb   = blk & 7;             // batch = XCD
    const int brow = nb * 4096 + (blk >> 3) * 64;
    const int w    = t >> 6;              // wave 0..7
    const int lane = t & 63;
    const int fr   = lane & 15, kq = lane >> 4;

    // ===== Phase 0: logits = query[64x256] @ Wcath^T + bcat -> sL =====
    {
        unsigned short* sQ = sS;          // [2][4096] fp32 swizzled (16KB)
        unsigned short* sW = sS + 8192;   // [2][4096] bf16 linear  (16KB)

        const int srow = t >> 3;          // 0..63
        const int scq  = (t & 7) ^ (srow & 7);
        const float* aG = query + (size_t)(brow + srow) * K + scq * 4;
        const unsigned short* wG = Wcath + (size_t)(t >> 2) * K + (t & 3) * 8;

        const int wr0 = w >> 2;           // 0..1 : 32-row half
        const int wc0 = w & 3;            // 0..3 : 32-col quarter

        f32x4 acc[2][2] = {};

#define STG0(buf, ks_) { const int k0_ = (ks_) * 32;                     \
       gl2lds16(aG + k0_, &sQ[(buf) * 4096 + t * 8]);                    \
       gl2lds16(wG + k0_, &sW[(buf) * 4096 + t * 8]); }

        STG0(0, 0);
        STG0(1, 1);

        for (int ks = 0; ks < NK; ++ks) {
            const int cur = ks & 1;
            if (ks < NK - 1) asm volatile("s_waitcnt vmcnt(2)" ::: "memory");
            else             asm volatile("s_waitcnt vmcnt(0)" ::: "memory");
            __builtin_amdgcn_s_barrier();
            __builtin_amdgcn_sched_barrier(0);

            bf16x8 af[2], bw[2];
#pragma unroll
            for (int m = 0; m < 2; ++m)
                af[m] = cvt_frag(&sQ[cur * 4096], wr0 * 32 + m * 16 + fr, kq);
#pragma unroll
            for (int n = 0; n < 2; ++n)
                bw[n] = *(const bf16x8*)&sW[cur * 4096 +
                        (wc0 * 32 + n * 16 + fr) * 32 + kq * 8];

#pragma unroll
            for (int m = 0; m < 2; ++m)
#pragma unroll
                for (int n = 0; n < 2; ++n)
                    acc[m][n] = __builtin_amdgcn_mfma_f32_16x16x32_bf16(
                        bw[n], af[m], acc[m][n], 0, 0, 0);

            __builtin_amdgcn_sched_barrier(0);
            __builtin_amdgcn_s_barrier();
            if (ks + 2 < NK) STG0(cur, ks + 2);
        }
#undef STG0

#pragma unroll
        for (int m = 0; m < 2; ++m) {
            const int row = wr0 * 32 + m * 16 + fr;
#pragma unroll
            for (int n = 0; n < 2; ++n) {
                const int colq = wc0 * 32 + n * 16 + kq * 4;
                const float4 b4 = *(const float4*)&bcat[colq];
                us4 o;
                o[0] = f2bf(acc[m][n][0] + b4.x);
                o[1] = f2bf(acc[m][n][1] + b4.y);
                o[2] = f2bf(acc[m][n][2] + b4.z);
                o[3] = f2bf(acc[m][n][3] + b4.w);
                *(us4*)&sL[row * 128 + colq] = o;
            }
        }
    }
    __syncthreads();                      // logits ready; sQ/sW dead

    // ===== Phase 1: sample 8 queries per wave, 2-query pipelined =====
    {
        const int tp  = lane & 31;
        const int pm  = tp >> 2, ppt = tp & 3;
        const int half = lane >> 5;
        const int c8   = lane & 31;
        const int mh   = c8 >> 2;
        const unsigned short* vbase = valueP + (size_t)nb * (PPIX * DM) + c8 * 8;

        for (int i = 0; i < 8; i += 2) {
            const int qa = w * 8 + i;
            const int qb = qa + 1;

            // ---- setup + issue gathers, query A ----
            us8 gA0[4], gB0[4]; float wA0[4], wB0[4];
            {
                const unsigned short* lg = sL + qa * 128;
                const int b = brow + qa;
                const float rx = refp[(size_t)b * 2 + 0];
                const float ry = refp[(size_t)b * 2 + 1];
                const float ox = bf2f(lg[pm * 8 + ppt * 2 + 0]);
                const float oy = bf2f(lg[pm * 8 + ppt * 2 + 1]);
                const float la = bf2f(lg[64 + tp]);
                const float x = fminf(fmaxf(fmaf(rx, (float)WW, ox) - 0.5f, -1.0f), 64.0f);
                const float y = fminf(fmaxf(fmaf(ry, (float)HH, oy) - 0.5f, -1.0f), 64.0f);
                float mx = fmaxf(la, __shfl_xor(la, 1));
                mx = fmaxf(mx, __shfl_xor(mx, 2));
                const float e = __expf(la - mx);
                float den = e + __shfl_xor(e, 1);
                den += __shfl_xor(den, 2);
                const float wgt = e / den;
#pragma unroll
                for (int p = 0; p < PP; ++p) {
                    const int   sl = mh * PP + p;
                    const float xp = __shfl(x, sl);
                    const float yp = __shfl(y, sl);
                    const float wp = __shfl(wgt, sl);
                    const float x0f = floorf(xp), y0f = floorf(yp);
                    const int   x0 = (int)x0f,   y0 = (int)y0f;
                    const float wx1 = xp - x0f,  wy1 = yp - y0f;
                    const float wy  = half ? wy1 : (1.f - wy1);
                    wA0[p] = wp * wy * (1.f - wx1);
                    wB0[p] = wp * wy * wx1;
                    const unsigned short* p0 =
                        vbase + (size_t)((y0 + 1 + half) * PW + (x0 + 1)) * DM;
                    gA0[p] = *(const us8*)(p0);
                    gB0[p] = *(const us8*)(p0 + DM);
                }
            }

            // ---- setup + issue gathers, query B (overlaps A's latency) ----
            us8 gA1[4], gB1[4]; float wA1[4], wB1[4];
            {
                const unsigned short* lg = sL + qb * 128;
                const int b = brow + qb;
                const float rx = refp[(size_t)b * 2 + 0];
                const float ry = refp[(size_t)b * 2 + 1];
                const float ox = bf2f(lg[pm * 8 + ppt * 2 + 0]);
                const float oy = bf2f(lg[pm * 8 + ppt * 2 + 1]);
                const float la = bf2f(lg[64 + tp]);
                const float x = fminf(fmaxf(fmaf(rx, (float)WW, ox) - 0.5f, -1.0f), 64.0f);
                const float y = fminf(fmaxf(fmaf(ry, (float)HH, oy) - 0.5f, -1.0f), 64.0f);
                float mx = fmaxf(la, __shfl_xor(la, 1));
                mx = fmaxf(mx, __shfl_xor(mx, 2));
                const float e = __expf(la - mx);
                float den = e + __shfl_xor(e, 1);
                den += __shfl_xor(den, 2);
                const float wgt = e / den;
#pragma unroll
                for (int p = 0; p < PP; ++p) {
                    const int   sl = mh * PP + p;
                    const float xp = __shfl(x, sl);
                    const float yp = __shfl(y, sl);
                    const float wp = __shfl(wgt, sl);
                    const float x0f = floorf(xp), y0f = floorf(yp);
                    const int   x0 = (int)x0f,   y0 = (int)y0f;
                    const float wx1 = xp - x0f,  wy1 = yp - y0f;
                    const float wy  = half ? wy1 : (1.f - wy1);
                    wA1[p] = wp * wy * (1.f - wx1);
                    wB1[p] = wp * wy * wx1;
                    const unsigned short* p0 =
                        vbase + (size_t)((y0 + 1 + half) * PW + (x0 + 1)) * DM;
                    gA1[p] = *(const us8*)(p0);
                    gB1[p] = *(const us8*)(p0 + DM);
                }
            }

            // ---- FMA + reduce + store, query A ----
            {
                float accv[8] = {};
#pragma unroll
                for (int p = 0; p < PP; ++p)
#pragma unroll
                    for (int j = 0; j < 8; ++j) {
                        accv[j] = fmaf(wA0[p], bf2f(gA0[p][j]), accv[j]);
                        accv[j] = fmaf(wB0[p], bf2f(gB0[p][j]), accv[j]);
                    }
#pragma unroll
                for (int j = 0; j < 8; ++j)
                    accv[j] += __shfl_xor(accv[j], 32);
                if (half == 0) {
                    us8 o;
#pragma unroll
                    for (int j = 0; j < 8; ++j) o[j] = f2bf(accv[j]);
                    *(us8*)&sS[qa * 256 + ((c8 ^ (qa & 7)) * 8)] = o;
                }
            }
            // ---- FMA + reduce + store, query B ----
            {
                float accv[8] = {};
#pragma unroll
                for (int p = 0; p < PP; ++p)
#pragma unroll
                    for (int j = 0; j < 8; ++j) {
                        accv[j] = fmaf(wA1[p], bf2f(gA1[p][j]), accv[j]);
                        accv[j] = fmaf(wB1[p], bf2f(gB1[p][j]), accv[j]);
                    }
#pragma unroll
                for (int j = 0; j < 8; ++j)
                    accv[j] += __shfl_xor(accv[j], 32);
                if (half == 0) {
                    us8 o;
#pragma unroll
                    for (int j = 0; j < 8; ++j) o[j] = f2bf(accv[j]);
                    *(us8*)&sS[qb * 256 + ((c8 ^ (qb & 7)) * 8)] = o;
                }
            }
        }
    }
    __syncthreads();                      // sampled tile complete in LDS

    // ===== Phase 2: out[64x256] = sS @ Woh^T + bo =====
    const unsigned short* bG = Woh + (size_t)(t >> 2) * K + (t & 3) * 8;
    const size_t rHalf = (size_t)128 * K;

    const int wr = w >> 2, wc = w & 3;    // wave tile 32 rows x 64 cols

    f32x4 acc[2][4] = {};

#define STAGEF(buf, ks_) { const int k0_ = (ks_) * 32;                   \
       gl2lds16(bG + k0_,         &sB[(buf) * 8192 + t * 8]);            \
       gl2lds16(bG + k0_ + rHalf, &sB[(buf) * 8192 + 4096 + t * 8]); }

    STAGEF(0, 0);
    STAGEF(1, 1);

    for (int ks = 0; ks < NK; ++ks) {
        const int cur = ks & 1;
        if (ks < NK - 1) asm volatile("s_waitcnt vmcnt(2)" ::: "memory");
        else             asm volatile("s_waitcnt vmcnt(0)" ::: "memory");
        __builtin_amdgcn_s_barrier();
        __builtin_amdgcn_sched_barrier(0);

        bf16x8 af[2], bfr[4];
#pragma unroll
        for (int m = 0; m < 2; ++m) {
            const int row = wr * 32 + m * 16 + fr;
            const int u   = (ks * 4 + kq) ^ (row & 7);
            af[m] = *(const bf16x8*)&sS[row * 256 + u * 8];
        }
#pragma unroll
        for (int n = 0; n < 4; ++n)
            bfr[n] = *(const bf16x8*)&sB[cur * 8192 + (wc * 64 + n * 16 + fr) * 32 + kq * 8];

#pragma unroll
        for (int m = 0; m < 2; ++m)
#pragma unroll
            for (int n = 0; n < 4; ++n)   // swapped: C[m16+fr][n16+kq4+j]
                acc[m][n] = __builtin_amdgcn_mfma_f32_16x16x32_bf16(
                    bfr[n], af[m], acc[m][n], 0, 0, 0);

        __builtin_amdgcn_sched_barrier(0);
        __builtin_amdgcn_s_barrier();
        if (ks + 2 < NK) STAGEF(cur, ks + 2);
    }
#undef STAGEF

#pragma unroll
    for (int m = 0; m < 2; ++m) {
        const int row = brow + wr * 32 + m * 16 + fr;
#pragma unroll
        for (int n = 0; n < 4; ++n) {
            const int colq = wc * 64 + n * 16 + kq * 4;
            const float4 bs = *(const float4*)&bo[colq];
            float4 o;
            o.x = acc[m][n][0] + bs.x; o.y = acc[m][n][1] + bs.y;
            o.z = acc[m][n][2] + bs.z; o.w = acc[m][n][3] + bs.w;
            *(float4*)&C[(size_t)row * DM + colq] = o;
        }
    }
}

// ---------------------------------------------------------------------------
extern "C" void kernel_launch(void* const* d_in, const int* in_sizes, int n_in,
                              void* d_out, int out_size, void* d_ws, size_t ws_size,
                              hipStream_t stream) {
    const float* query  = (const float*)d_in[0];   // [8,4096,256]
    const float* refp   = (const float*)d_in[1];   // [8,4096,2]
    const float* inputf = (const float*)d_in[2];   // [8,4096,256]
    const float* Wv   = (const float*)d_in[5];     // [256,256]
    const float* bv   = (const float*)d_in[6];     // [256]
    const float* Woff = (const float*)d_in[7];     // [64,256]
    const float* boff = (const float*)d_in[8];     // [64]
    const float* Wa   = (const float*)d_in[9];     // [32,256]
    const float* ba   = (const float*)d_in[10];    // [32]
    const float* Wo   = (const float*)d_in[11];    // [256,256]
    const float* bo   = (const float*)d_in[12];    // [256]
    float* out = (float*)d_out;

    // workspace layout (ushort units)
    unsigned short* valueP = (unsigned short*)d_ws;            //  9,193,472
    unsigned short* Wvh    = valueP + (size_t)NB * PPIX * DM;  //     65,536
    unsigned short* Woh    = Wvh    + 65536;                   //     65,536
    unsigned short* Wcath  = Woh    + 65536;                   //     32,768
    float*          bcat   = (float*)(Wcath + 32768);          //        128

    // 1. prep: weight bf16 conversion + image border zero
    prep_kernel<<<1427, 256, 0, stream>>>(Wv, Wo, Woff, Wa, boff, ba,
                                          Wvh, Woh, Wcath, bcat, valueP);

    // 2. value GEMM (BM=64, batch<->XCD affine, counted vmcnt)
    value_gemm<<<1024, 256, 0, stream>>>(inputf, Wvh, bv, valueP);

    // 3. fused logits GEMM + sampling + out GEMM (80 KB dyn LDS)
    fused_lso<<<512, 512, 81920, stream>>>(query, refp, valueP, Wcath, bcat,
                                           Woh, bo, out);
}

// Round 21
// 58.343 us; speedup vs baseline: 1.1101x; 1.0020x over previous
//
#include <hip/hip_runtime.h>
#include <math.h>

// Problem constants (fixed by the reference)
#define NB   8        // batch
#define LQN  4096     // queries
#define DM   256      // d_model
#define MH   8        // heads
#define PP   4        // points
#define HH   64       // H
#define WW   64       // W
#define PW   67       // padded image width/height (x,y in -1..65)
#define PPIX (PW*PW)  // 4489 padded pixels per batch

typedef __bf16 bf16x8 __attribute__((ext_vector_type(8)));
typedef float  f32x4  __attribute__((ext_vector_type(4)));
typedef unsigned short us8 __attribute__((ext_vector_type(8)));
typedef unsigned short us4 __attribute__((ext_vector_type(4)));

__device__ __forceinline__ unsigned short f2bf(float f) {   // RNE fp32 -> bf16 bits
    unsigned u = __float_as_uint(f);
    u += 0x7FFFu + ((u >> 16) & 1u);
    return (unsigned short)(u >> 16);
}
__device__ __forceinline__ float bf2f(unsigned short b) {
    return __uint_as_float((unsigned)b << 16);
}

__device__ __forceinline__ void gl2lds16(const void* g, unsigned short* l) {
    __builtin_amdgcn_global_load_lds(
        (const __attribute__((address_space(1))) void*)g,
        (__attribute__((address_space(3))) void*)l,
        16, 0, 0);
}

// Convert a swizzled fp32 LDS row-pair (two 16B units) to a bf16x8 fragment.
// LDS layout: [rows][8 units of 16B], unit for k-quad q of row r at
// r*8 + (q ^ (r&7)); write side is linear DMA dest + XOR-swizzled global src.
__device__ __forceinline__ bf16x8 cvt_frag(const unsigned short* s, int row, int kq) {
    const int u0 = row * 8 + ((kq * 2) ^ (row & 7));
    const int u1 = u0 ^ 1;
    const f32x4 a0 = *(const f32x4*)&s[u0 * 8];
    const f32x4 a1 = *(const f32x4*)&s[u1 * 8];
    bf16x8 v;
    v[0] = (__bf16)a0[0]; v[1] = (__bf16)a0[1];
    v[2] = (__bf16)a0[2]; v[3] = (__bf16)a0[3];
    v[4] = (__bf16)a1[0]; v[5] = (__bf16)a1[1];
    v[6] = (__bf16)a1[2]; v[7] = (__bf16)a1[3];
    return v;
}

// ---------------------------------------------------------------------------
// Prep: weight bf16 conversion (Wvh [256][256]; Woh [256][256]; Wcath
// [128][256] rows 96-127 zero; bcat fp32[128]) + padded-image border zero.
// ---------------------------------------------------------------------------
__global__ __launch_bounds__(256)
void prep_kernel(const float* __restrict__ Wv, const float* __restrict__ Wo,
                 const float* __restrict__ Woff, const float* __restrict__ Wa,
                 const float* __restrict__ boff, const float* __restrict__ ba,
                 unsigned short* __restrict__ Wvh, unsigned short* __restrict__ Woh,
                 unsigned short* __restrict__ Wcath, float* __restrict__ bcat,
                 unsigned short* __restrict__ valueP) {
    const int i = blockIdx.x * 256 + threadIdx.x;
    if (i < 65536) {
        Wvh[i] = f2bf(Wv[i]);
    } else if (i < 131072) {
        const int j = i - 65536;
        Woh[j] = f2bf(Wo[j]);
    } else if (i < 163840) {
        const int j = i - 131072, n = j >> 8, k = j & 255;
        const float v = (n < 64) ? Woff[n * 256 + k]
                                 : ((n < 96) ? Wa[(n - 64) * 256 + k] : 0.f);
        Wcath[j] = f2bf(v);
    } else if (i < 163968) {
        const int n = i - 163840;
        bcat[n] = (n < 64) ? boff[n] : ((n < 96) ? ba[n - 64] : 0.f);
    } else if (i < 163968 + 201216) {
        const int j   = i - 163968;
        const int c4  = j & 63;
        const int pix = j >> 6;
        const int n   = pix / 393;
        const int r   = pix - n * 393;
        int x, y;
        if (r < 201) {
            const int q = r / 67;
            y = (q == 0) ? 0 : (q == 1 ? 65 : 66);
            x = r - q * 67;
        } else {
            const int q = r - 201;
            y = 1 + q / 3;
            const int s = q - (q / 3) * 3;
            x = (s == 0) ? 0 : (s == 1 ? 65 : 66);
        }
        const size_t addr = ((size_t)n * PPIX + (size_t)y * PW + x) * DM + c4 * 4;
        *(ushort4*)&valueP[addr] = make_ushort4(0, 0, 0, 0);
    }
}

// ---------------------------------------------------------------------------
// Value GEMM (proven): BM=64/BN=128, batch<->XCD affine, 2-deep counted
// vmcnt pipeline, A fp32 gl2lds swizzled + read cvt, bf16 scatter into the
// padded value image. + T5 setprio around the MFMA cluster.
// ---------------------------------------------------------------------------
__global__ __launch_bounds__(256, 4)
void value_gemm(const float* __restrict__ Ain,
                const unsigned short* __restrict__ Wvh,
                const float* __restrict__ bv,
                unsigned short* __restrict__ valueP) {
    constexpr int K = 256, NK = 8;
    __shared__ unsigned short sA[2][4096];   // [64][32] fp32, swizzled units
    __shared__ unsigned short sB[2][4096];   // [128][32] bf16 linear

    const int t   = threadIdx.x;
    const int blk = blockIdx.x;              // 0..1023
    const int xb  = blk & 7;                 // batch = XCD
    const int idx = blk >> 3;                // 0..127
    const int brow = xb * 4096 + (idx >> 1) * 64;
    const int bcol = (idx & 1) * 128;

    const int srow = t >> 3;
    const int scq  = (t & 7) ^ (srow & 7);
    const float* aG = Ain + (size_t)(brow + srow) * K + scq * 4;
    const size_t aI = (size_t)32 * K;

    const unsigned short* bG = Wvh + (size_t)(bcol + (t >> 2)) * K + (t & 3) * 8;
    const size_t bI = (size_t)64 * K;

    const int l   = t & 63;
    const int wid = t >> 6;
    const int wr  = wid >> 1, wc = wid & 1;
    const int fr  = l & 15,   kq = l >> 4;

    f32x4 acc[2][4] = {};

#define STAGE(buf, ks_) { const int k0_ = (ks_) * 32;                    \
       gl2lds16(aG + k0_,      &sA[buf][t * 8]);                         \
       gl2lds16(aG + k0_ + aI, &sA[buf][2048 + t * 8]);                  \
       gl2lds16(bG + k0_,      &sB[buf][t * 8]);                         \
       gl2lds16(bG + k0_ + bI, &sB[buf][2048 + t * 8]); }

    STAGE(0, 0);
    STAGE(1, 1);

    for (int ks = 0; ks < NK; ++ks) {
        const int cur = ks & 1;
        if (ks < NK - 1) asm volatile("s_waitcnt vmcnt(4)" ::: "memory");
        else             asm volatile("s_waitcnt vmcnt(0)" ::: "memory");
        __builtin_amdgcn_s_barrier();
        __builtin_amdgcn_sched_barrier(0);

        bf16x8 af[2], bf_[4];
#pragma unroll
        for (int m = 0; m < 2; ++m)
            af[m]  = cvt_frag(sA[cur], wr * 32 + m * 16 + fr, kq);
#pragma unroll
        for (int n = 0; n < 4; ++n)
            bf_[n] = *(const bf16x8*)&sB[cur][(wc * 64 + n * 16 + fr) * 32 + kq * 8];

        __builtin_amdgcn_s_setprio(1);
#pragma unroll
        for (int m = 0; m < 2; ++m)
#pragma unroll
            for (int n = 0; n < 4; ++n)
                acc[m][n] = __builtin_amdgcn_mfma_f32_16x16x32_bf16(
                    bf_[n], af[m], acc[m][n], 0, 0, 0);
        __builtin_amdgcn_s_setprio(0);

        __builtin_amdgcn_sched_barrier(0);
        __builtin_amdgcn_s_barrier();
        if (ks + 2 < NK) STAGE(cur, ks + 2);
    }
#undef STAGE

#pragma unroll
    for (int m = 0; m < 2; ++m) {
        const int row = brow + wr * 32 + m * 16 + fr;
        const int nb_ = row >> 12;
        const int pix = row & 4095;
        const int y   = pix >> 6, x = pix & 63;
        const size_t rbase =
            ((size_t)nb_ * PPIX + (size_t)(y + 1) * PW + (x + 1)) * DM;
#pragma unroll
        for (int n = 0; n < 4; ++n) {
            const int colq = bcol + wc * 64 + n * 16 + kq * 4;
            const float4 b4 = *(const float4*)&bv[colq];
            us4 o;
            o[0] = f2bf(acc[m][n][0] + b4.x);
            o[1] = f2bf(acc[m][n][1] + b4.y);
            o[2] = f2bf(acc[m][n][2] + b4.z);
            o[3] = f2bf(acc[m][n][3] + b4.w);
            *(us4*)&valueP[rbase + colq] = o;
        }
    }
}

// ---------------------------------------------------------------------------
// FUSED logits-GEMM + sampling + out-GEMM, 64-query tile. 512 thr = 8 waves,
// 80 KB dyn LDS -> 2 blocks/CU. Batch-affine (batch = blk&7).
// Phase 0: logits[64][128] = query @ Wcath^T + bcat -> LDS sL (bf16).
// Phase 1: 2-query software-pipelined sampling.
// Phase 2: out[64x256] = sS @ Woh^T + bo; B lane-linear gl2lds dbuf.
// T5 setprio around MFMA clusters (inter-block wave diversity at 2 blk/CU).
// ---------------------------------------------------------------------------
__global__ __launch_bounds__(512, 4)
void fused_lso(const float* __restrict__ query, const float* __restrict__ refp,
               const unsigned short* __restrict__ valueP,
               const unsigned short* __restrict__ Wcath,
               const float* __restrict__ bcat,
               const unsigned short* __restrict__ Woh,
               const float* __restrict__ bo, float* __restrict__ C) {
    constexpr int K = 256, NK = 8;
    extern __shared__ unsigned short smem[];
    unsigned short* sS = smem;            // 32KB: ph0 A/B dbuf, ph1 sampled[64][256]
    unsigned short* sB = smem + 16384;    // 32KB: ph2 Woh dbuf [2][8192]
    unsigned short* sL = smem + 32768;    // 16KB: logits [64][128]

    const int t    = threadIdx.x;
    const int blk  = blockIdx.x;          // 0..511
    const int nb   = blk & 7;             // batch = XCD
    const int brow = nb * 4096 + (blk >> 3) * 64;
    const int w    = t >> 6;              // wave 0..7
    const int lane = t & 63;
    const int fr   = lane & 15, kq = lane >> 4;

    // ===== Phase 0: logits = query[64x256] @ Wcath^T + bcat -> sL =====
    {
        unsigned short* sQ = sS;          // [2][4096] fp32 swizzled (16KB)
        unsigned short* sW = sS + 8192;   // [2][4096] bf16 linear  (16KB)

        const int srow = t >> 3;          // 0..63
        const int scq  = (t & 7) ^ (srow & 7);
        const float* aG = query + (size_t)(brow + srow) * K + scq * 4;
        const unsigned short* wG = Wcath + (size_t)(t >> 2) * K + (t & 3) * 8;

        const int wr0 = w >> 2;           // 0..1 : 32-row half
        const int wc0 = w & 3;            // 0..3 : 32-col quarter

        f32x4 acc[2][2] = {};

#define STG0(buf, ks_) { const int k0_ = (ks_) * 32;                     \
       gl2lds16(aG + k0_, &sQ[(buf) * 4096 + t * 8]);                    \
       gl2lds16(wG + k0_, &sW[(buf) * 4096 + t * 8]); }

        STG0(0, 0);
        STG0(1, 1);

        for (int ks = 0; ks < NK; ++ks) {
            const int cur = ks & 1;
            if (ks < NK - 1) asm volatile("s_waitcnt vmcnt(2)" ::: "memory");
            else             asm volatile("s_waitcnt vmcnt(0)" ::: "memory");
            __builtin_amdgcn_s_barrier();
            __builtin_amdgcn_sched_barrier(0);

            bf16x8 af[2], bw[2];
#pragma unroll
            for (int m = 0; m < 2; ++m)
                af[m] = cvt_frag(&sQ[cur * 4096], wr0 * 32 + m * 16 + fr, kq);
#pragma unroll
            for (int n = 0; n < 2; ++n)
                bw[n] = *(const bf16x8*)&sW[cur * 4096 +
                        (wc0 * 32 + n * 16 + fr) * 32 + kq * 8];

            __builtin_amdgcn_s_setprio(1);
#pragma unroll
            for (int m = 0; m < 2; ++m)
#pragma unroll
                for (int n = 0; n < 2; ++n)
                    acc[m][n] = __builtin_amdgcn_mfma_f32_16x16x32_bf16(
                        bw[n], af[m], acc[m][n], 0, 0, 0);
            __builtin_amdgcn_s_setprio(0);

            __builtin_amdgcn_sched_barrier(0);
            __builtin_amdgcn_s_barrier();
            if (ks + 2 < NK) STG0(cur, ks + 2);
        }
#undef STG0

#pragma unroll
        for (int m = 0; m < 2; ++m) {
            const int row = wr0 * 32 + m * 16 + fr;
#pragma unroll
            for (int n = 0; n < 2; ++n) {
                const int colq = wc0 * 32 + n * 16 + kq * 4;
                const float4 b4 = *(const float4*)&bcat[colq];
                us4 o;
                o[0] = f2bf(acc[m][n][0] + b4.x);
                o[1] = f2bf(acc[m][n][1] + b4.y);
                o[2] = f2bf(acc[m][n][2] + b4.z);
                o[3] = f2bf(acc[m][n][3] + b4.w);
                *(us4*)&sL[row * 128 + colq] = o;
            }
        }
    }
    __syncthreads();                      // logits ready; sQ/sW dead

    // ===== Phase 1: sample 8 queries per wave, 2-query pipelined =====
    {
        const int tp  = lane & 31;
        const int pm  = tp >> 2, ppt = tp & 3;
        const int half = lane >> 5;
        const int c8   = lane & 31;
        const int mh   = c8 >> 2;
        const unsigned short* vbase = valueP + (size_t)nb * (PPIX * DM) + c8 * 8;

        for (int i = 0; i < 8; i += 2) {
            const int qa = w * 8 + i;
            const int qb = qa + 1;

            // ---- setup + issue gathers, query A ----
            us8 gA0[4], gB0[4]; float wA0[4], wB0[4];
            {
                const unsigned short* lg = sL + qa * 128;
                const int b = brow + qa;
                const float rx = refp[(size_t)b * 2 + 0];
                const float ry = refp[(size_t)b * 2 + 1];
                const float ox = bf2f(lg[pm * 8 + ppt * 2 + 0]);
                const float oy = bf2f(lg[pm * 8 + ppt * 2 + 1]);
                const float la = bf2f(lg[64 + tp]);
                const float x = fminf(fmaxf(fmaf(rx, (float)WW, ox) - 0.5f, -1.0f), 64.0f);
                const float y = fminf(fmaxf(fmaf(ry, (float)HH, oy) - 0.5f, -1.0f), 64.0f);
                float mx = fmaxf(la, __shfl_xor(la, 1));
                mx = fmaxf(mx, __shfl_xor(mx, 2));
                const float e = __expf(la - mx);
                float den = e + __shfl_xor(e, 1);
                den += __shfl_xor(den, 2);
                const float wgt = e / den;
#pragma unroll
                for (int p = 0; p < PP; ++p) {
                    const int   sl = mh * PP + p;
                    const float xp = __shfl(x, sl);
                    const float yp = __shfl(y, sl);
                    const float wp = __shfl(wgt, sl);
                    const float x0f = floorf(xp), y0f = floorf(yp);
                    const int   x0 = (int)x0f,   y0 = (int)y0f;
                    const float wx1 = xp - x0f,  wy1 = yp - y0f;
                    const float wy  = half ? wy1 : (1.f - wy1);
                    wA0[p] = wp * wy * (1.f - wx1);
                    wB0[p] = wp * wy * wx1;
                    const unsigned short* p0 =
                        vbase + (size_t)((y0 + 1 + half) * PW + (x0 + 1)) * DM;
                    gA0[p] = *(const us8*)(p0);
                    gB0[p] = *(const us8*)(p0 + DM);
                }
            }

            // ---- setup + issue gathers, query B (overlaps A's latency) ----
            us8 gA1[4], gB1[4]; float wA1[4], wB1[4];
            {
                const unsigned short* lg = sL + qb * 128;
                const int b = brow + qb;
                const float rx = refp[(size_t)b * 2 + 0];
                const float ry = refp[(size_t)b * 2 + 1];
                const float ox = bf2f(lg[pm * 8 + ppt * 2 + 0]);
                const float oy = bf2f(lg[pm * 8 + ppt * 2 + 1]);
                const float la = bf2f(lg[64 + tp]);
                const float x = fminf(fmaxf(fmaf(rx, (float)WW, ox) - 0.5f, -1.0f), 64.0f);
                const float y = fminf(fmaxf(fmaf(ry, (float)HH, oy) - 0.5f, -1.0f), 64.0f);
                float mx = fmaxf(la, __shfl_xor(la, 1));
                mx = fmaxf(mx, __shfl_xor(mx, 2));
                const float e = __expf(la - mx);
                float den = e + __shfl_xor(e, 1);
                den += __shfl_xor(den, 2);
                const float wgt = e / den;
#pragma unroll
                for (int p = 0; p < PP; ++p) {
                    const int   sl = mh * PP + p;
                    const float xp = __shfl(x, sl);
                    const float yp = __shfl(y, sl);
                    const float wp = __shfl(wgt, sl);
                    const float x0f = floorf(xp), y0f = floorf(yp);
                    const int   x0 = (int)x0f,   y0 = (int)y0f;
                    const float wx1 = xp - x0f,  wy1 = yp - y0f;
                    const float wy  = half ? wy1 : (1.f - wy1);
                    wA1[p] = wp * wy * (1.f - wx1);
                    wB1[p] = wp * wy * wx1;
                    const unsigned short* p0 =
                        vbase + (size_t)((y0 + 1 + half) * PW + (x0 + 1)) * DM;
                    gA1[p] = *(const us8*)(p0);
                    gB1[p] = *(const us8*)(p0 + DM);
                }
            }

            // ---- FMA + reduce + store, query A ----
            {
                float accv[8] = {};
#pragma unroll
                for (int p = 0; p < PP; ++p)
#pragma unroll
                    for (int j = 0; j < 8; ++j) {
                        accv[j] = fmaf(wA0[p], bf2f(gA0[p][j]), accv[j]);
                        accv[j] = fmaf(wB0[p], bf2f(gB0[p][j]), accv[j]);
                    }
#pragma unroll
                for (int j = 0; j < 8; ++j)
                    accv[j] += __shfl_xor(accv[j], 32);
                if (half == 0) {
                    us8 o;
#pragma unroll
                    for (int j = 0; j < 8; ++j) o[j] = f2bf(accv[j]);
                    *(us8*)&sS[qa * 256 + ((c8 ^ (qa & 7)) * 8)] = o;
                }
            }
            // ---- FMA + reduce + store, query B ----
            {
                float accv[8] = {};
#pragma unroll
                for (int p = 0; p < PP; ++p)
#pragma unroll
                    for (int j = 0; j < 8; ++j) {
                        accv[j] = fmaf(wA1[p], bf2f(gA1[p][j]), accv[j]);
                        accv[j] = fmaf(wB1[p], bf2f(gB1[p][j]), accv[j]);
                    }
#pragma unroll
                for (int j = 0; j < 8; ++j)
                    accv[j] += __shfl_xor(accv[j], 32);
                if (half == 0) {
                    us8 o;
#pragma unroll
                    for (int j = 0; j < 8; ++j) o[j] = f2bf(accv[j]);
                    *(us8*)&sS[qb * 256 + ((c8 ^ (qb & 7)) * 8)] = o;
                }
            }
        }
    }
    __syncthreads();                      // sampled tile complete in LDS

    // ===== Phase 2: out[64x256] = sS @ Woh^T + bo =====
    const unsigned short* bG = Woh + (size_t)(t >> 2) * K + (t & 3) * 8;
    const size_t rHalf = (size_t)128 * K;

    const int wr = w >> 2, wc = w & 3;    // wave tile 32 rows x 64 cols

    f32x4 acc[2][4] = {};

#define STAGEF(buf, ks_) { const int k0_ = (ks_) * 32;                   \
       gl2lds16(bG + k0_,         &sB[(buf) * 8192 + t * 8]);            \
       gl2lds16(bG + k0_ + rHalf, &sB[(buf) * 8192 + 4096 + t * 8]); }

    STAGEF(0, 0);
    STAGEF(1, 1);

    for (int ks = 0; ks < NK; ++ks) {
        const int cur = ks & 1;
        if (ks < NK - 1) asm volatile("s_waitcnt vmcnt(2)" ::: "memory");
        else             asm volatile("s_waitcnt vmcnt(0)" ::: "memory");
        __builtin_amdgcn_s_barrier();
        __builtin_amdgcn_sched_barrier(0);

        bf16x8 af[2], bfr[4];
#pragma unroll
        for (int m = 0; m < 2; ++m) {
            const int row = wr * 32 + m * 16 + fr;
            const int u   = (ks * 4 + kq) ^ (row & 7);
            af[m] = *(const bf16x8*)&sS[row * 256 + u * 8];
        }
#pragma unroll
        for (int n = 0; n < 4; ++n)
            bfr[n] = *(const bf16x8*)&sB[cur * 8192 + (wc * 64 + n * 16 + fr) * 32 + kq * 8];

        __builtin_amdgcn_s_setprio(1);
#pragma unroll
        for (int m = 0; m < 2; ++m)
#pragma unroll
            for (int n = 0; n < 4; ++n)   // swapped: C[m16+fr][n16+kq4+j]
                acc[m][n] = __builtin_amdgcn_mfma_f32_16x16x32_bf16(
                    bfr[n], af[m], acc[m][n], 0, 0, 0);
        __builtin_amdgcn_s_setprio(0);

        __builtin_amdgcn_sched_barrier(0);
        __builtin_amdgcn_s_barrier();
        if (ks + 2 < NK) STAGEF(cur, ks + 2);
    }
#undef STAGEF

#pragma unroll
    for (int m = 0; m < 2; ++m) {
        const int row = brow + wr * 32 + m * 16 + fr;
#pragma unroll
        for (int n = 0; n < 4; ++n) {
            const int colq = wc * 64 + n * 16 + kq * 4;
            const float4 bs = *(const float4*)&bo[colq];
            float4 o;
            o.x = acc[m][n][0] + bs.x; o.y = acc[m][n][1] + bs.y;
            o.z = acc[m][n][2] + bs.z; o.w = acc[m][n][3] + bs.w;
            *(float4*)&C[(size_t)row * DM + colq] = o;
        }
    }
}

// ---------------------------------------------------------------------------
extern "C" void kernel_launch(void* const* d_in, const int* in_sizes, int n_in,
                              void* d_out, int out_size, void* d_ws, size_t ws_size,
                              hipStream_t stream) {
    const float* query  = (const float*)d_in[0];   // [8,4096,256]
    const float* refp   = (const float*)d_in[1];   // [8,4096,2]
    const float* inputf = (const float*)d_in[2];   // [8,4096,256]
    const float* Wv   = (const float*)d_in[5];     // [256,256]
    const float* bv   = (const float*)d_in[6];     // [256]
    const float* Woff = (const float*)d_in[7];     // [64,256]
    const float* boff = (const float*)d_in[8];     // [64]
    const float* Wa   = (const float*)d_in[9];     // [32,256]
    const float* ba   = (const float*)d_in[10];    // [32]
    const float* Wo   = (const float*)d_in[11];    // [256,256]
    const float* bo   = (const float*)d_in[12];    // [256]
    float* out = (float*)d_out;

    // workspace layout (ushort units)
    unsigned short* valueP = (unsigned short*)d_ws;            //  9,193,472
    unsigned short* Wvh    = valueP + (size_t)NB * PPIX * DM;  //     65,536
    unsigned short* Woh    = Wvh    + 65536;                   //     65,536
    unsigned short* Wcath  = Woh    + 65536;                   //     32,768
    float*          bcat   = (float*)(Wcath + 32768);          //        128

    // 1. prep: weight bf16 conversion + image border zero
    prep_kernel<<<1427, 256, 0, stream>>>(Wv, Wo, Woff, Wa, boff, ba,
                                          Wvh, Woh, Wcath, bcat, valueP);

    // 2. value GEMM (BM=64, batch<->XCD affine, counted vmcnt)
    value_gemm<<<1024, 256, 0, stream>>>(inputf, Wvh, bv, valueP);

    // 3. fused logits GEMM + sampling + out GEMM (80 KB dyn LDS)
    fused_lso<<<512, 512, 81920, stream>>>(query, refp, valueP, Wcath, bcat,
                                           Woh, bo, out);
}